// Round 2
// baseline (283.609 us; speedup 1.0000x reference)
//
#include <hip/hip_runtime.h>

#define DEV_INLINE __device__ __forceinline__

// Problem dims (fixed by setup_inputs)
constexpr int B = 16, T = 4096, C = 512, K = 3;
constexpr int NC = 256;          // chunks along T (R1: 64 -> 256 for occupancy)
constexpr int L  = T / NC;       // 16 steps per chunk
constexpr int C4 = C / 4;        // 128 float4 lanes across channels
constexpr int GS = 16;           // chunks per scan-group
constexpr int G  = NC / GS;      // 16 groups
constexpr float EPS = 1e-4f;

// ws layout (in floats):
//   [TAB_A,    +K*C) : a[k][c]            (clamped sigmoid)
//   [TAB_AL,   +K*C) : a^L                (chunk multiplier)
//   [TAB_A16,  +K*C) : a^(L*GS) = a^256   (group multiplier)
//   [TAB_MIX,  +K*C) : softmax mix transposed to [k][c]
//   [CARRY,  +B*NC*K*C) : pass1 chunk suffixes -> pass2a rewrites to group-local incoming
//   [GCARRY, +B*G*K*C)  : pass2a group totals -> pass2b rewrites to group incoming states
constexpr size_t TAB_A   = 0;
constexpr size_t TAB_AL  = (size_t)1 * K * C;
constexpr size_t TAB_A16 = (size_t)2 * K * C;
constexpr size_t TAB_MIX = (size_t)3 * K * C;
constexpr size_t CARRY   = (size_t)4 * K * C;                    // 24 KiB in, 16B aligned
constexpr size_t GCARRY  = CARRY + (size_t)B * NC * K * C;       // after 25.2 MB carry

DEV_INLINE float4 f4mul(float4 a, float4 b) {
  return make_float4(a.x * b.x, a.y * b.y, a.z * b.z, a.w * b.w);
}
DEV_INLINE float4 f4fma(float4 a, float4 b, float4 c) {
  return make_float4(fmaf(a.x, b.x, c.x), fmaf(a.y, b.y, c.y),
                     fmaf(a.z, b.z, c.z), fmaf(a.w, b.w, c.w));
}
DEV_INLINE float4 f4add(float4 a, float4 b) {
  return make_float4(a.x + b.x, a.y + b.y, a.z + b.z, a.w + b.w);
}
DEV_INLINE float4 f4onesub(float4 a) {
  return make_float4(1.f - a.x, 1.f - a.y, 1.f - a.z, 1.f - a.w);
}
DEV_INLINE float4 f4zero() { return make_float4(0.f, 0.f, 0.f, 0.f); }
DEV_INLINE float4 f4one()  { return make_float4(1.f, 1.f, 1.f, 1.f); }

// ---------------- prep: per-channel tables ----------------
__global__ void ema_prep(const float* __restrict__ logit_alpha,
                         const float* __restrict__ mix_logits,
                         float* __restrict__ ws) {
  int c = blockIdx.x * blockDim.x + threadIdx.x;
  if (c >= C) return;
  #pragma unroll
  for (int k = 0; k < K; ++k) {
    float la = logit_alpha[k * C + c];
    float a  = 1.0f / (1.0f + __expf(-la));
    a = fminf(fmaxf(a, EPS), 1.0f - EPS);
    ws[TAB_A + k * C + c] = a;
    float p = a;                 // a^L, L = 16 = 2^4
    #pragma unroll
    for (int s = 0; s < 4; ++s) p = p * p;
    ws[TAB_AL + k * C + c] = p;
    #pragma unroll
    for (int s = 0; s < 4; ++s) p = p * p;  // a^256
    ws[TAB_A16 + k * C + c] = p;
  }
  float m0 = mix_logits[c * K + 0];
  float m1 = mix_logits[c * K + 1];
  float m2 = mix_logits[c * K + 2];
  float mx = fmaxf(m0, fmaxf(m1, m2));
  float e0 = __expf(m0 - mx), e1 = __expf(m1 - mx), e2 = __expf(m2 - mx);
  float inv = 1.0f / (e0 + e1 + e2);
  ws[TAB_MIX + 0 * C + c] = e0 * inv;
  ws[TAB_MIX + 1 * C + c] = e1 * inv;
  ws[TAB_MIX + 2 * C + c] = e2 * inv;
}

// ---------------- pass1: per-chunk local suffix (zero-init EMA over the chunk) ----------------
__global__ __launch_bounds__(128, 8) void ema_pass1(const float* __restrict__ x,
                                                    float* __restrict__ ws) {
  const int c4 = threadIdx.x;          // 0..C4-1
  const int bi = blockIdx.x;           // b*NC + chunk
  const int i  = bi & (NC - 1);

  const float4* aT = (const float4*)(ws + TAB_A);
  const float4 a0 = aT[0 * C4 + c4];
  const float4 a1 = aT[1 * C4 + c4];
  const float4 a2 = aT[2 * C4 + c4];
  const float4 b0 = f4onesub(a0), b1 = f4onesub(a1), b2 = f4onesub(a2);

  const float4* xb = (const float4*)x + (size_t)bi * L * C4 + c4;

  float4 y0, y1, y2;
  int jstart;
  if (i == 0) {                        // chunk 0: y[0] = x[0] exactly
    float4 x0 = xb[0];
    y0 = x0; y1 = x0; y2 = x0;
    jstart = 1;
  } else {
    y0 = f4zero(); y1 = y0; y2 = y0;
    jstart = 0;
  }

  #pragma unroll 4
  for (int j = jstart; j < L; ++j) {
    float4 xv = xb[(size_t)j * C4];
    y0 = f4fma(a0, y0, f4mul(b0, xv));
    y1 = f4fma(a1, y1, f4mul(b1, xv));
    y2 = f4fma(a2, y2, f4mul(b2, xv));
  }

  float4* carry = (float4*)(ws + CARRY);
  const size_t cb = ((size_t)bi * K) * C4 + c4;
  carry[cb + 0 * C4] = y0;
  carry[cb + 1 * C4] = y1;
  carry[cb + 2 * C4] = y2;
}

// ---------------- pass2a: within-group scan of chunk suffixes ----------------
// carry[b][i][k][c] (chunk suffix s_i) -> group-local incoming state (zero-init prefix);
// writes the group's 16-chunk total to gcarry[b][g][k][c].
__global__ __launch_bounds__(256) void ema_pass2a(float* __restrict__ ws) {
  int idx = blockIdx.x * blockDim.x + threadIdx.x;   // over B*G*K*C4
  const int c4 = idx & (C4 - 1);
  int r = idx >> 7;
  const int k = r % K; r /= K;
  const int g = r & (G - 1);
  const int b = r >> 4;

  const float4 A = ((const float4*)(ws + TAB_AL))[k * C4 + c4];
  float4* carry = (float4*)(ws + CARRY);
  float4* gcarry = (float4*)(ws + GCARRY);

  const size_t cstride = (size_t)K * C4;             // per-chunk stride
  size_t slot = ((size_t)(b * NC + g * GS) * K + k) * (size_t)C4 + c4;

  float4 P = f4zero();
  #pragma unroll 4
  for (int j = 0; j < GS; ++j) {
    float4 t = carry[slot];
    carry[slot] = P;                                 // group-local incoming of chunk j
    P = f4fma(A, P, t);
    slot += cstride;
  }
  gcarry[((size_t)(b * G + g) * K + k) * C4 + c4] = P;
}

// ---------------- pass2b: scan group totals -> group incoming states ----------------
__global__ __launch_bounds__(256) void ema_pass2b(float* __restrict__ ws) {
  int idx = blockIdx.x * blockDim.x + threadIdx.x;   // over B*K*C4
  const int c4 = idx & (C4 - 1);
  const int k  = (idx >> 7) % K;
  const int b  = idx / (C4 * K);

  const float4 A16 = ((const float4*)(ws + TAB_A16))[k * C4 + c4];
  float4* gcarry = (float4*)(ws + GCARRY);
  const size_t gstride = (size_t)K * C4;
  size_t slot = ((size_t)(b * G) * K + k) * (size_t)C4 + c4;

  float4 S = f4zero();
  #pragma unroll 4
  for (int g = 0; g < G; ++g) {
    float4 t = gcarry[slot];
    gcarry[slot] = S;                                // incoming state of group g
    S = f4fma(A16, S, t);
    slot += gstride;
  }
}

// ---------------- pass3: S = A^(jl*L)*SG + local_in, re-run chunk, fuse mix, store ----------------
__global__ __launch_bounds__(128, 6) void ema_pass3(const float* __restrict__ x,
                                                    const float* __restrict__ ws,
                                                    float* __restrict__ out) {
  const int c4 = threadIdx.x;
  const int bi = blockIdx.x;
  const int i  = bi & (NC - 1);
  const int b  = bi >> 8;              // NC = 256
  const int g  = i >> 4;               // group
  const int jl = i & (GS - 1);         // chunk index within group (wave-uniform)

  const float4* aT = (const float4*)(ws + TAB_A);
  const float4* mT = (const float4*)(ws + TAB_MIX);
  const float4 a0 = aT[0 * C4 + c4];
  const float4 a1 = aT[1 * C4 + c4];
  const float4 a2 = aT[2 * C4 + c4];
  const float4 b0 = f4onesub(a0), b1 = f4onesub(a1), b2 = f4onesub(a2);
  const float4 m0 = mT[0 * C4 + c4];
  const float4 m1 = mT[1 * C4 + c4];
  const float4 m2 = mT[2 * C4 + c4];

  const float4* xb = (const float4*)x + (size_t)bi * L * C4 + c4;
  float4*       ob = (float4*)out     + (size_t)bi * L * C4 + c4;

  float4 y0, y1, y2;
  int jstart;
  if (i == 0) {
    float4 x0 = xb[0];
    y0 = x0; y1 = x0; y2 = x0;
    ob[0] = f4fma(m0, y0, f4fma(m1, y1, f4mul(m2, y2)));
    jstart = 1;
  } else {
    const float4* carry  = (const float4*)(ws + CARRY);
    const float4* gcarry = (const float4*)(ws + GCARRY);
    const float4* alT    = (const float4*)(ws + TAB_AL);

    // local_in (group-local incoming state of this chunk)
    const size_t cb = ((size_t)bi * K) * C4 + c4;
    float4 l0 = carry[cb + 0 * C4];
    float4 l1 = carry[cb + 1 * C4];
    float4 l2 = carry[cb + 2 * C4];
    // group incoming state
    const size_t gb = ((size_t)(b * G + g) * K) * C4 + c4;
    float4 s0 = gcarry[gb + 0 * C4];
    float4 s1 = gcarry[gb + 1 * C4];
    float4 s2 = gcarry[gb + 2 * C4];
    // Apow = (a^L)^jl via binary exponentiation (jl wave-uniform, 4 bits)
    float4 p0 = f4one(), p1 = f4one(), p2 = f4one();
    float4 q0 = alT[0 * C4 + c4];
    float4 q1 = alT[1 * C4 + c4];
    float4 q2 = alT[2 * C4 + c4];
    #pragma unroll
    for (int bit = 0; bit < 4; ++bit) {
      if ((jl >> bit) & 1) { p0 = f4mul(p0, q0); p1 = f4mul(p1, q1); p2 = f4mul(p2, q2); }
      if (bit < 3) { q0 = f4mul(q0, q0); q1 = f4mul(q1, q1); q2 = f4mul(q2, q2); }
    }
    // S = Apow*SG + local_in
    y0 = f4fma(p0, s0, l0);
    y1 = f4fma(p1, s1, l1);
    y2 = f4fma(p2, s2, l2);
    jstart = 0;
  }

  #pragma unroll 4
  for (int j = jstart; j < L; ++j) {
    float4 xv = xb[(size_t)j * C4];
    y0 = f4fma(a0, y0, f4mul(b0, xv));
    y1 = f4fma(a1, y1, f4mul(b1, xv));
    y2 = f4fma(a2, y2, f4mul(b2, xv));
    ob[(size_t)j * C4] = f4fma(m0, y0, f4fma(m1, y1, f4mul(m2, y2)));
  }
}

extern "C" void kernel_launch(void* const* d_in, const int* in_sizes, int n_in,
                              void* d_out, int out_size, void* d_ws, size_t ws_size,
                              hipStream_t stream) {
  const float* x           = (const float*)d_in[0];
  const float* logit_alpha = (const float*)d_in[1];
  const float* mix_logits  = (const float*)d_in[2];
  float* out = (float*)d_out;
  float* ws  = (float*)d_ws;

  ema_prep<<<(C + 255) / 256, 256, 0, stream>>>(logit_alpha, mix_logits, ws);
  ema_pass1<<<B * NC, 128, 0, stream>>>(x, ws);
  ema_pass2a<<<(B * G * K * C4) / 256, 256, 0, stream>>>(ws);
  ema_pass2b<<<(B * K * C4 + 255) / 256, 256, 0, stream>>>(ws);
  ema_pass3<<<B * NC, 128, 0, stream>>>(x, ws, out);
}